// Round 17
// baseline (397.710 us; speedup 1.0000x reference)
//
#include <hip/hip_runtime.h>
#include <hip/hip_fp16.h>

#define BB 4096
#define NN 4096
#define RPB 4            // rows per block in k_K
#define RPI 16           // rows per producer block in k_itf
#define NSL 256          // partial slices (= producer blocks)
#define NRED 64          // reducer blocks in k_itf
#define RPP 8            // rows per block in k_P
#define NTSLOT 60        // k_P: slots >= NTSLOT use nt K loads
#define CNT_INTS (10 * 8 * 16)   // 10 iters x 8 spread counters x 16-int pad

// XCD-contiguous swizzle for k_K (round-robin dispatch: bid%8 -> XCD bid%8).
__device__ __forceinline__ int swzK(int bid) { return (bid & 7) * 128 + (bid >> 3); }

// non-temporal helpers via native clang vector types
typedef float vf4 __attribute__((ext_vector_type(4)));
typedef float vf2 __attribute__((ext_vector_type(2)));
typedef int   vi4 __attribute__((ext_vector_type(4)));
typedef float fv2 __attribute__((ext_vector_type(2)));
__device__ __forceinline__ float4 ntl4(const float4* p) {
    vf4 r = __builtin_nontemporal_load((const vf4*)p);
    return *(float4*)&r;
}
__device__ __forceinline__ int4 ntl4i(const int4* p) {
    vi4 r = __builtin_nontemporal_load((const vi4*)p);
    return *(int4*)&r;
}
__device__ __forceinline__ void nts4(float4* p, float4 v) {
    __builtin_nontemporal_store(*(vf4*)&v, (vf4*)p);
}
__device__ __forceinline__ void nts2(float2* p, float2 v) {
    __builtin_nontemporal_store(*(vf2*)&v, (vf2*)p);
}

// fp8 e4m3 (OCP) decode: 4 packed fp8 -> 4 floats (HW v_cvt_pk_f32_fp8)
__device__ __forceinline__ void dec4(int w, float* f) {
    fv2 lo = __builtin_amdgcn_cvt_pk_f32_fp8(w, false);
    fv2 hi = __builtin_amdgcn_cvt_pk_f32_fp8(w, true);
    f[0] = lo.x; f[1] = lo.y; f[2] = hi.x; f[3] = hi.y;
}

// 8-B device-scope (write-through / coherent) atomic store + load
__device__ __forceinline__ void ast8(unsigned long long* p, float a, float b) {
    union { float2 f; unsigned long long q; } u;
    u.f = make_float2(a, b);
    __hip_atomic_store(p, u.q, __ATOMIC_RELAXED, __HIP_MEMORY_SCOPE_AGENT);
}
__device__ __forceinline__ float2 ald8(const unsigned long long* p) {
    union { float2 f; unsigned long long q; } u;
    u.q = __hip_atomic_load(p, __ATOMIC_RELAXED, __HIP_MEMORY_SCOPE_AGENT);
    return u.f;
}

// ---------------- mean(D) reduction + v=1 init + counter zero ----------------
__global__ __launch_bounds__(256) void k_mean(
        const float* __restrict__ Dt, float* __restrict__ dsum,
        float* __restrict__ v, int* __restrict__ cnt) {
    const int tid = blockIdx.x * blockDim.x + threadIdx.x;
    const int gs = gridDim.x * blockDim.x;
    if (tid < NN) v[tid] = 1.0f;
    if (tid < CNT_INTS) cnt[tid] = 0;
    const float4* D4 = (const float4*)Dt;
    const int total4 = (BB * NN) / 4;
    float s = 0.f;
    for (int i = tid; i < total4; i += gs) {
        float4 d = ntl4(&D4[i]);
        s += (d.x + d.y) + (d.z + d.w);
    }
    #pragma unroll
    for (int off = 32; off > 0; off >>= 1) s += __shfl_down(s, off, 64);
    __shared__ float ls[4];
    if ((threadIdx.x & 63) == 0) ls[threadIdx.x >> 6] = s;
    __syncthreads();
    if (threadIdx.x == 0) atomicAdd(dsum, (ls[0] + ls[1]) + (ls[2] + ls[3]));
}

// ---------------- K = exp(5*dot - 5*D/mean): fp16 K + fp8 K8=fp8(16K) ------
__global__ __launch_bounds__(256) void k_K(
        const int* __restrict__ users, const int* __restrict__ pois,
        const float* __restrict__ Dt, const float* __restrict__ poi_emb,
        const float* __restrict__ user_emb, const float* __restrict__ dsum,
        __half* __restrict__ K, unsigned char* __restrict__ K8) {
    __shared__ __half slut[RPB][NN];      // 32 KB
    __shared__ float ues[RPB * 16];
    const int t = threadIdx.x;
    const int b0 = swzK(blockIdx.x) * RPB;
    if (t < RPB * 16) {
        int r = t >> 4, d = t & 15;
        ues[t] = user_emb[(size_t)users[b0 + r] * 16 + d];
    }
    __syncthreads();
    float ue[RPB][16];
    #pragma unroll
    for (int r = 0; r < RPB; r++)
        #pragma unroll
        for (int d = 0; d < 16; d++) ue[r][d] = ues[r * 16 + d];

    const float4* pe4 = (const float4*)poi_emb;
    for (int j = t; j < NN; j += 256) {
        float4 p0 = pe4[j * 4 + 0];
        float4 p1 = pe4[j * 4 + 1];
        float4 p2 = pe4[j * 4 + 2];
        float4 p3 = pe4[j * 4 + 3];
        #pragma unroll
        for (int r = 0; r < RPB; r++) {
            float acc = p0.x*ue[r][0]  + p0.y*ue[r][1]  + p0.z*ue[r][2]  + p0.w*ue[r][3]
                      + p1.x*ue[r][4]  + p1.y*ue[r][5]  + p1.z*ue[r][6]  + p1.w*ue[r][7]
                      + p2.x*ue[r][8]  + p2.y*ue[r][9]  + p2.z*ue[r][10] + p2.w*ue[r][11]
                      + p3.x*ue[r][12] + p3.y*ue[r][13] + p3.z*ue[r][14] + p3.w*ue[r][15];
            slut[r][j] = __float2half(acc);
        }
    }
    __syncthreads();                       // lut read-only from here on
    const float cc = 5.0f * 16777216.0f / dsum[0];   // 5 / mean(D)
    #pragma unroll
    for (int r = 0; r < RPB; r++) {
        const size_t base = (size_t)(b0 + r) * NN;
        const int4*   p4 = (const int4*)(pois + base);
        const float4* d4 = (const float4*)(Dt + base);
        #pragma unroll
        for (int i = 0; i < NN / 4 / 256; i++) {     // 4
            const int q = t + i * 256;
            int4   ci = ntl4i(&p4[q]);
            float4 cd = ntl4(&d4[q]);
            float k0 = __expf(5.0f * __half2float(slut[r][ci.x]) - cc * cd.x);
            float k1 = __expf(5.0f * __half2float(slut[r][ci.y]) - cc * cd.y);
            float k2 = __expf(5.0f * __half2float(slut[r][ci.z]) - cc * cd.z);
            float k3 = __expf(5.0f * __half2float(slut[r][ci.w]) - cc * cd.w);
            __half2 ha = __floats2half2_rn(k0, k1);
            __half2 hb = __floats2half2_rn(k2, k3);
            float2 w16;
            *(__half2*)&w16.x = ha;
            *(__half2*)&w16.y = hb;
            nts2((float2*)&K[base + 4 * (size_t)q], w16);
            int w8 = __builtin_amdgcn_cvt_pk_fp8_f32(16.f * k0, 16.f * k1, 0, false);
            w8 = __builtin_amdgcn_cvt_pk_fp8_f32(16.f * k2, 16.f * k3, w8, true);
            __builtin_nontemporal_store(w8, &((int*)(K8 + base))[q]);
        }
    }
}

// ---------------- fused sinkhorn iteration: ONE launch per iteration -------
// blocks 0..255 (producers): u from v, column partials -> coherent stores,
//   arrival counter, exit. Never wait -> deadlock-free.
// blocks 256..319 (reducers): poll counters == 256, reduce 64 cols each,
//   write v. v is read by producers strictly before reducers overwrite it.
__global__ __launch_bounds__(1024) void k_itf(
        const unsigned char* __restrict__ K8, float* __restrict__ v,
        float* __restrict__ part, float* __restrict__ u,
        const float* __restrict__ cap, int* __restrict__ cnt) {
    const int t = threadIdx.x;
    if (blockIdx.x < NSL) {
        // ================= producer =================
        const int c = t & 511;
        const int rh = t >> 9;
        const int sb = ((int)blockIdx.x & 7) * 32 + ((int)blockIdx.x >> 3);
        const int r0 = sb * RPI + rh * 8;

        const float4* w4 = (const float4*)v;
        float4 w0 = w4[2 * c], w1 = w4[2 * c + 1];

        uint2 h8[8];
        #pragma unroll
        for (int r = 0; r < 8; r++)
            h8[r] = ((const uint2*)(K8 + (size_t)(r0 + r) * NN))[c];

        float acc[8];
        #pragma unroll
        for (int r = 0; r < 8; r++) {
            float f[8];
            dec4((int)h8[r].x, f);
            dec4((int)h8[r].y, f + 4);
            acc[r] = f[0]*w0.x + f[1]*w0.y + f[2]*w0.z + f[3]*w0.w
                   + f[4]*w1.x + f[5]*w1.y + f[6]*w1.z + f[7]*w1.w;
        }
        #pragma unroll
        for (int off = 32; off > 0; off >>= 1)
            #pragma unroll
            for (int r = 0; r < 8; r++) acc[r] += __shfl_down(acc[r], off, 64);
        __shared__ float ls[16][8];
        __shared__ float us[16];
        if ((t & 63) == 0)
            #pragma unroll
            for (int r = 0; r < 8; r++) ls[t >> 6][r] = acc[r];
        __syncthreads();
        if (t < 16) {
            const int wb = (t < 8) ? 0 : 8;
            const int rr = (t < 8) ? t : (t - 8);
            float s = 0.f;
            #pragma unroll
            for (int wv = 0; wv < 8; wv++) s += ls[wb + wv][rr];
            float uu = 1.0f / s;              // = u_true/16 (K8 = 16K)
            us[t] = uu;
            u[sb * RPI + t] = 16.0f * uu;     // true u for k_P
        }
        __syncthreads();

        float4 A0 = make_float4(0, 0, 0, 0), A1 = A0;
        #pragma unroll
        for (int r = 0; r < 8; r++) {
            const float ur = us[rh * 8 + r];
            float f[8];
            dec4((int)h8[r].x, f);
            dec4((int)h8[r].y, f + 4);
            A0.x += ur * f[0]; A0.y += ur * f[1]; A0.z += ur * f[2]; A0.w += ur * f[3];
            A1.x += ur * f[4]; A1.y += ur * f[5]; A1.z += ur * f[6]; A1.w += ur * f[7];
        }
        __shared__ float4 ps[512][2];         // 16 KB
        if (rh == 1) { ps[c][0] = A0; ps[c][1] = A1; }
        __syncthreads();
        if (rh == 0) {
            float4 B0 = ps[c][0], B1 = ps[c][1];
            A0.x += B0.x; A0.y += B0.y; A0.z += B0.z; A0.w += B0.w;
            A1.x += B1.x; A1.y += B1.y; A1.z += B1.z; A1.w += B1.w;
            unsigned long long* pq =
                (unsigned long long*)(part + (size_t)sb * NN) + 4 * c;
            ast8(pq + 0, A0.x, A0.y);
            ast8(pq + 1, A0.z, A0.w);
            ast8(pq + 2, A1.x, A1.y);
            ast8(pq + 3, A1.z, A1.w);
        }
        __syncthreads();   // implies vmcnt(0): all coherent stores ack'd
        if (t == 0) {
            asm volatile("s_waitcnt vmcnt(0)" ::: "memory");
            __hip_atomic_fetch_add(&cnt[((int)blockIdx.x & 7) * 16], 1,
                                   __ATOMIC_RELAXED, __HIP_MEMORY_SCOPE_AGENT);
        }
    } else {
        // ================= reducer =================
        const int rb = (int)blockIdx.x - NSL;      // 0..63, owns cols [64rb,64rb+64)
        if (t == 0) {
            int s;
            do {
                s = 0;
                #pragma unroll
                for (int x = 0; x < 8; x++)
                    s += __hip_atomic_load(&cnt[x * 16], __ATOMIC_RELAXED,
                                           __HIP_MEMORY_SCOPE_AGENT);
                if (s < NSL) __builtin_amdgcn_s_sleep(16);
            } while (s < NSL);
        }
        __syncthreads();
        const int p = t & 31;                      // pair -> cols 64rb+2p, +1
        const int sg = t >> 5;                     // 0..31
        const unsigned long long* pq = (const unsigned long long*)part;
        float a0 = 0.f, a1 = 0.f;
        #pragma unroll
        for (int k = 0; k < 8; k++) {
            float2 f = ald8(&pq[(size_t)(sg + 32 * k) * (NN / 2) + 32 * rb + p]);
            a0 += f.x; a1 += f.y;
        }
        __shared__ float2 rsum[32][32];
        rsum[sg][p] = make_float2(a0, a1);
        __syncthreads();
        if (t < 32) {
            float s0 = 0.f, s1 = 0.f;
            #pragma unroll
            for (int g = 0; g < 32; g++) {
                float2 f = rsum[g][t];
                s0 += f.x; s1 += f.y;
            }
            const int col = 64 * rb + 2 * t;
            v[col]     = cap[col]     / s0;
            v[col + 1] = cap[col + 1] / s1;
        }
    }
}

// ---------------- P = K * u[b] * v[n]: fp16 K, nt writes ----------
__global__ __launch_bounds__(256) void k_P(
        const __half* __restrict__ K, const float* __restrict__ u,
        const float* __restrict__ v, float* __restrict__ P) {
    const int t = threadIdx.x;
    const int slot = blockIdx.x >> 3;
    const int sb = (blockIdx.x & 7) * 64 + slot;
    const int r0 = sb * RPP;
    const bool nt = (slot >= NTSLOT);
    const float4* v4 = (const float4*)v;
    float4 va0 = v4[2 * t],       va1 = v4[2 * t + 1];
    float4 vb0 = v4[512 + 2 * t], vb1 = v4[512 + 2 * t + 1];
    #pragma unroll 2
    for (int r = 0; r < RPP; r++) {
        const int b = r0 + r;
        const float ub = u[b];
        const size_t base = (size_t)b * NN;
        const float4* k4 = (const float4*)(K + base);
        float4 raw0 = nt ? ntl4(&k4[t])       : k4[t];
        float4 raw1 = nt ? ntl4(&k4[256 + t]) : k4[256 + t];
        const __half2* ha = (const __half2*)&raw0;
        const __half2* hb = (const __half2*)&raw1;
        float2 f0 = __half22float2(ha[0]);
        float2 f1 = __half22float2(ha[1]);
        float2 f2 = __half22float2(ha[2]);
        float2 f3 = __half22float2(ha[3]);
        float2 g0 = __half22float2(hb[0]);
        float2 g1 = __half22float2(hb[1]);
        float2 g2 = __half22float2(hb[2]);
        float2 g3 = __half22float2(hb[3]);
        float4* P4 = (float4*)(P + base);
        nts4(&P4[2*t],       make_float4(f0.x*ub*va0.x, f0.y*ub*va0.y, f1.x*ub*va0.z, f1.y*ub*va0.w));
        nts4(&P4[2*t+1],     make_float4(f2.x*ub*va1.x, f2.y*ub*va1.y, f3.x*ub*va1.z, f3.y*ub*va1.w));
        nts4(&P4[512+2*t],   make_float4(g0.x*ub*vb0.x, g0.y*ub*vb0.y, g1.x*ub*vb0.z, g1.y*ub*vb0.w));
        nts4(&P4[512+2*t+1], make_float4(g2.x*ub*vb1.x, g2.y*ub*vb1.y, g3.x*ub*vb1.z, g3.y*ub*vb1.w));
    }
}

extern "C" void kernel_launch(void* const* d_in, const int* in_sizes, int n_in,
                              void* d_out, int out_size, void* d_ws, size_t ws_size,
                              hipStream_t stream) {
    const int*   users    = (const int*)d_in[0];
    const int*   pois     = (const int*)d_in[1];
    const float* Dt       = (const float*)d_in[2];
    const float* poi_emb  = (const float*)d_in[3];
    const float* user_emb = (const float*)d_in[4];
    const float* cap      = (const float*)d_in[5];
    float* out = (float*)d_out;

    float*  wsf  = (float*)d_ws;
    float*  dsum = wsf;                         // [64]
    int*    cnt  = (int*)(wsf + 64);            // [CNT_INTS]
    float*  u    = wsf + 64 + CNT_INTS;         // [BB]
    float*  v    = u + BB;                      // [NN]
    __half* Kh   = (__half*)(v + NN);           // [BB*NN] fp16 = 33.5 MB
    float*  part = (float*)d_out;               // [NSL*NN] fp32 = 4.2 MB
    unsigned char* K8 = (unsigned char*)(part + (size_t)NSL * NN);  // 16.8 MB
    // part + K8 = 21 MB in d_out (67 MB); both dead before k_P writes out.

    (void)hipMemsetAsync(dsum, 0, sizeof(float), stream);
    k_mean<<<2048, 256, 0, stream>>>(Dt, dsum, v, cnt);
    k_K<<<BB / RPB, 256, 0, stream>>>(users, pois, Dt, poi_emb, user_emb, dsum, Kh, K8);
    for (int it = 0; it < 10; it++) {
        k_itf<<<NSL + NRED, 1024, 0, stream>>>(K8, v, part, u, cap, cnt + it * 128);
    }
    k_P<<<BB / RPP, 256, 0, stream>>>(Kh, u, v, out);
}

// Round 18
// 353.572 us; speedup vs baseline: 1.1248x; 1.1248x over previous
//
#include <hip/hip_runtime.h>
#include <hip/hip_fp16.h>

#define BB 4096
#define NN 4096
#define RPB 4            // rows per block in k_K
#define RPI 16           // rows per block in k_it (1024 threads, 2 row-halves)
#define IBLK (BB / RPI)  // 256 k_it blocks
#define NSL IBLK         // 256 partial slices
#define RPP 2            // rows per block in k_P (2048 blocks)

// XCD-contiguous swizzle for k_K (round-robin dispatch: bid%8 -> XCD bid%8).
__device__ __forceinline__ int swzK(int bid) { return (bid & 7) * 128 + (bid >> 3); }

// broadcast a block-uniform float into an SGPR (exact)
__device__ __forceinline__ float rfl(float x) {
    return __int_as_float(__builtin_amdgcn_readfirstlane(__float_as_int(x)));
}

// non-temporal helpers via native clang vector types
typedef float vf4 __attribute__((ext_vector_type(4)));
typedef float vf2 __attribute__((ext_vector_type(2)));
typedef int   vi4 __attribute__((ext_vector_type(4)));
typedef float fv2 __attribute__((ext_vector_type(2)));
__device__ __forceinline__ float4 ntl4(const float4* p) {
    vf4 r = __builtin_nontemporal_load((const vf4*)p);
    return *(float4*)&r;
}
__device__ __forceinline__ int4 ntl4i(const int4* p) {
    vi4 r = __builtin_nontemporal_load((const vi4*)p);
    return *(int4*)&r;
}
__device__ __forceinline__ void nts4(float4* p, float4 v) {
    __builtin_nontemporal_store(*(vf4*)&v, (vf4*)p);
}
__device__ __forceinline__ void nts2(float2* p, float2 v) {
    __builtin_nontemporal_store(*(vf2*)&v, (vf2*)p);
}

// fp8 e4m3 (OCP) decode: 4 packed fp8 -> 4 floats (HW v_cvt_pk_f32_fp8)
__device__ __forceinline__ void dec4(int w, float* f) {
    fv2 lo = __builtin_amdgcn_cvt_pk_f32_fp8(w, false);
    fv2 hi = __builtin_amdgcn_cvt_pk_f32_fp8(w, true);
    f[0] = lo.x; f[1] = lo.y; f[2] = hi.x; f[3] = hi.y;
}

// ---------------- mean(D) reduction + v=1 init ----------------
__global__ __launch_bounds__(256) void k_mean(
        const float* __restrict__ Dt, float* __restrict__ dsum,
        float* __restrict__ v) {
    const int tid = blockIdx.x * blockDim.x + threadIdx.x;
    const int gs = gridDim.x * blockDim.x;
    if (tid < NN) v[tid] = 1.0f;
    const float4* D4 = (const float4*)Dt;
    const int total4 = (BB * NN) / 4;
    float s = 0.f;
    for (int i = tid; i < total4; i += gs) {
        float4 d = ntl4(&D4[i]);
        s += (d.x + d.y) + (d.z + d.w);
    }
    #pragma unroll
    for (int off = 32; off > 0; off >>= 1) s += __shfl_down(s, off, 64);
    __shared__ float ls[4];
    if ((threadIdx.x & 63) == 0) ls[threadIdx.x >> 6] = s;
    __syncthreads();
    if (threadIdx.x == 0) atomicAdd(dsum, (ls[0] + ls[1]) + (ls[2] + ls[3]));
}

// ---------------- K = exp(5*dot - 5*D/mean): fp16 K + fp8 K8=fp8(16K) ------
// ue in SGPRs via rfl (frees ~64 VGPRs for load pipelining in phase 2).
__global__ __launch_bounds__(256) void k_K(
        const int* __restrict__ users, const int* __restrict__ pois,
        const float* __restrict__ Dt, const float* __restrict__ poi_emb,
        const float* __restrict__ user_emb, const float* __restrict__ dsum,
        __half* __restrict__ K, unsigned char* __restrict__ K8) {
    __shared__ __half slut[RPB][NN];      // 32 KB
    __shared__ float ues[RPB * 16];
    const int t = threadIdx.x;
    const int b0 = swzK(blockIdx.x) * RPB;
    if (t < RPB * 16) {
        int r = t >> 4, d = t & 15;
        ues[t] = user_emb[(size_t)users[b0 + r] * 16 + d];
    }
    __syncthreads();
    float ue[RPB][16];                    // block-uniform -> SGPRs
    #pragma unroll
    for (int r = 0; r < RPB; r++)
        #pragma unroll
        for (int d = 0; d < 16; d++) ue[r][d] = rfl(ues[r * 16 + d]);

    const float4* pe4 = (const float4*)poi_emb;
    for (int j = t; j < NN; j += 256) {
        float4 p0 = pe4[j * 4 + 0];
        float4 p1 = pe4[j * 4 + 1];
        float4 p2 = pe4[j * 4 + 2];
        float4 p3 = pe4[j * 4 + 3];
        #pragma unroll
        for (int r = 0; r < RPB; r++) {
            float acc = p0.x*ue[r][0]  + p0.y*ue[r][1]  + p0.z*ue[r][2]  + p0.w*ue[r][3]
                      + p1.x*ue[r][4]  + p1.y*ue[r][5]  + p1.z*ue[r][6]  + p1.w*ue[r][7]
                      + p2.x*ue[r][8]  + p2.y*ue[r][9]  + p2.z*ue[r][10] + p2.w*ue[r][11]
                      + p3.x*ue[r][12] + p3.y*ue[r][13] + p3.z*ue[r][14] + p3.w*ue[r][15];
            slut[r][j] = __float2half(acc);
        }
    }
    __syncthreads();                       // lut read-only from here on
    const float cc = 5.0f * 16777216.0f / dsum[0];   // 5 / mean(D)
    #pragma unroll
    for (int r = 0; r < RPB; r++) {
        const size_t base = (size_t)(b0 + r) * NN;
        const int4*   p4 = (const int4*)(pois + base);
        const float4* d4 = (const float4*)(Dt + base);
        #pragma unroll
        for (int i = 0; i < NN / 4 / 256; i++) {     // 4
            const int q = t + i * 256;
            int4   ci = ntl4i(&p4[q]);
            float4 cd = ntl4(&d4[q]);
            float k0 = __expf(5.0f * __half2float(slut[r][ci.x]) - cc * cd.x);
            float k1 = __expf(5.0f * __half2float(slut[r][ci.y]) - cc * cd.y);
            float k2 = __expf(5.0f * __half2float(slut[r][ci.z]) - cc * cd.z);
            float k3 = __expf(5.0f * __half2float(slut[r][ci.w]) - cc * cd.w);
            __half2 ha = __floats2half2_rn(k0, k1);
            __half2 hb = __floats2half2_rn(k2, k3);
            float2 w16;
            *(__half2*)&w16.x = ha;
            *(__half2*)&w16.y = hb;
            nts2((float2*)&K[base + 4 * (size_t)q], w16);
            int w8 = __builtin_amdgcn_cvt_pk_fp8_f32(16.f * k0, 16.f * k1, 0, false);
            w8 = __builtin_amdgcn_cvt_pk_fp8_f32(16.f * k2, 16.f * k3, w8, true);
            __builtin_nontemporal_store(w8, &((int*)(K8 + base))[q]);
        }
    }
}

// ---------------- fused sinkhorn iteration (256 x 1024, fp8 K) -------------
// K8 loads (L3 long-pole) issued before the L2-warm v broadcast loads.
__global__ __launch_bounds__(1024) void k_it(
        const unsigned char* __restrict__ K8, const float* __restrict__ v,
        float* __restrict__ part, float* __restrict__ u) {
    const int t = threadIdx.x;            // 0..1023
    const int c = t & 511;
    const int rh = t >> 9;
    const int sb = (blockIdx.x & 7) * 32 + (blockIdx.x >> 3);  // XCD swizzle
    const int r0 = sb * RPI + rh * 8;

    uint2 h8[8];
    #pragma unroll
    for (int r = 0; r < 8; r++)
        h8[r] = ((const uint2*)(K8 + (size_t)(r0 + r) * NN))[c];

    const float4* w4 = (const float4*)v;
    float4 w0 = w4[2 * c], w1 = w4[2 * c + 1];

    float acc[8];
    #pragma unroll
    for (int r = 0; r < 8; r++) {
        float f[8];
        dec4((int)h8[r].x, f);
        dec4((int)h8[r].y, f + 4);
        acc[r] = f[0]*w0.x + f[1]*w0.y + f[2]*w0.z + f[3]*w0.w
               + f[4]*w1.x + f[5]*w1.y + f[6]*w1.z + f[7]*w1.w;
    }
    #pragma unroll
    for (int off = 32; off > 0; off >>= 1)
        #pragma unroll
        for (int r = 0; r < 8; r++) acc[r] += __shfl_down(acc[r], off, 64);
    __shared__ float ls[16][8];
    __shared__ float us[16];
    if ((t & 63) == 0)
        #pragma unroll
        for (int r = 0; r < 8; r++) ls[t >> 6][r] = acc[r];
    __syncthreads();
    if (t < 16) {
        const int wb = (t < 8) ? 0 : 8;
        const int rr = (t < 8) ? t : (t - 8);
        float s = 0.f;
        #pragma unroll
        for (int wv = 0; wv < 8; wv++) s += ls[wb + wv][rr];
        float uu = 1.0f / s;              // = u_true/16 (K8 = 16K)
        us[t] = uu;
        u[sb * RPI + t] = 16.0f * uu;     // true u for k_P
    }
    __syncthreads();

    float4 A0 = make_float4(0, 0, 0, 0), A1 = A0;
    #pragma unroll
    for (int r = 0; r < 8; r++) {
        const float ur = us[rh * 8 + r];
        float f[8];
        dec4((int)h8[r].x, f);
        dec4((int)h8[r].y, f + 4);
        A0.x += ur * f[0]; A0.y += ur * f[1]; A0.z += ur * f[2]; A0.w += ur * f[3];
        A1.x += ur * f[4]; A1.y += ur * f[5]; A1.z += ur * f[6]; A1.w += ur * f[7];
    }
    __shared__ float4 ps[512][2];         // 16 KB
    if (rh == 1) { ps[c][0] = A0; ps[c][1] = A1; }
    __syncthreads();
    if (rh == 0) {
        float4 B0 = ps[c][0], B1 = ps[c][1];
        A0.x += B0.x; A0.y += B0.y; A0.z += B0.z; A0.w += B0.w;
        A1.x += B1.x; A1.y += B1.y; A1.z += B1.z; A1.w += B1.w;
        float4* p4 = (float4*)(part + (size_t)sb * NN);
        nts4(&p4[2 * c],     A0);
        nts4(&p4[2 * c + 1], A1);
    }
}

// ---------------- v[n] = cap[n] / sum_sb part[sb][n] (256 slices) ----------
__global__ __launch_bounds__(256) void k_red(
        const float* __restrict__ part, const float* __restrict__ cap,
        float* __restrict__ v) {
    const int t = threadIdx.x;
    const int g = blockIdx.x;
    const int j = t & 7;
    const int s = t >> 3;
    const float4* p4 = (const float4*)part;
    float4 a = make_float4(0, 0, 0, 0);
    #pragma unroll
    for (int i = 0; i < NSL / 32; i++) {             // 8
        float4 x = ntl4(&p4[(size_t)(s + 32 * i) * (NN / 4) + g * 8 + j]);
        a.x += x.x; a.y += x.y; a.z += x.z; a.w += x.w;
    }
    __shared__ float4 red[32][8];
    red[s][j] = a;
    __syncthreads();
    if (t < 8) {
        float4 b = red[0][t];
        #pragma unroll
        for (int s2 = 1; s2 < 32; s2++) {
            float4 x = red[s2][t];
            b.x += x.x; b.y += x.y; b.z += x.z; b.w += x.w;
        }
        float4 cc = ((const float4*)cap)[g * 8 + t];
        ((float4*)v)[g * 8 + t] =
            make_float4(cc.x / b.x, cc.y / b.y, cc.z / b.z, cc.w / b.w);
    }
}

// ---------------- P = K * u[b] * v[n]: RPP=2, all-nt ----------
__global__ __launch_bounds__(256) void k_P(
        const __half* __restrict__ K, const float* __restrict__ u,
        const float* __restrict__ v, float* __restrict__ P) {
    const int t = threadIdx.x;
    const int sb = (blockIdx.x & 7) * 256 + (blockIdx.x >> 3);   // 2048 blocks
    const int r0 = sb * RPP;
    const float4* v4 = (const float4*)v;
    float4 va0 = v4[2 * t],       va1 = v4[2 * t + 1];
    float4 vb0 = v4[512 + 2 * t], vb1 = v4[512 + 2 * t + 1];
    #pragma unroll
    for (int r = 0; r < RPP; r++) {
        const int b = r0 + r;
        const float ub = u[b];
        const size_t base = (size_t)b * NN;
        const float4* k4 = (const float4*)(K + base);
        float4 raw0 = ntl4(&k4[t]);
        float4 raw1 = ntl4(&k4[256 + t]);
        const __half2* ha = (const __half2*)&raw0;
        const __half2* hb = (const __half2*)&raw1;
        float2 f0 = __half22float2(ha[0]);
        float2 f1 = __half22float2(ha[1]);
        float2 f2 = __half22float2(ha[2]);
        float2 f3 = __half22float2(ha[3]);
        float2 g0 = __half22float2(hb[0]);
        float2 g1 = __half22float2(hb[1]);
        float2 g2 = __half22float2(hb[2]);
        float2 g3 = __half22float2(hb[3]);
        float4* P4 = (float4*)(P + base);
        nts4(&P4[2*t],       make_float4(f0.x*ub*va0.x, f0.y*ub*va0.y, f1.x*ub*va0.z, f1.y*ub*va0.w));
        nts4(&P4[2*t+1],     make_float4(f2.x*ub*va1.x, f2.y*ub*va1.y, f3.x*ub*va1.z, f3.y*ub*va1.w));
        nts4(&P4[512+2*t],   make_float4(g0.x*ub*vb0.x, g0.y*ub*vb0.y, g1.x*ub*vb0.z, g1.y*ub*vb0.w));
        nts4(&P4[512+2*t+1], make_float4(g2.x*ub*vb1.x, g2.y*ub*vb1.y, g3.x*ub*vb1.z, g3.y*ub*vb1.w));
    }
}

extern "C" void kernel_launch(void* const* d_in, const int* in_sizes, int n_in,
                              void* d_out, int out_size, void* d_ws, size_t ws_size,
                              hipStream_t stream) {
    const int*   users    = (const int*)d_in[0];
    const int*   pois     = (const int*)d_in[1];
    const float* Dt       = (const float*)d_in[2];
    const float* poi_emb  = (const float*)d_in[3];
    const float* user_emb = (const float*)d_in[4];
    const float* cap      = (const float*)d_in[5];
    float* out = (float*)d_out;

    float*  wsf  = (float*)d_ws;
    float*  dsum = wsf;                         // [64]
    float*  u    = wsf + 64;                    // [BB]
    float*  v    = wsf + 64 + BB;               // [NN]
    __half* Kh   = (__half*)(wsf + 64 + BB + NN);   // [BB*NN] fp16 = 33.5 MB
    float*  part = (float*)d_out;               // [NSL*NN] fp32 = 4.2 MB
    unsigned char* K8 = (unsigned char*)(part + (size_t)NSL * NN);  // 16.8 MB
    // part + K8 = 21 MB in d_out (67 MB); both dead before k_P writes out.

    (void)hipMemsetAsync(dsum, 0, sizeof(float), stream);
    k_mean<<<2048, 256, 0, stream>>>(Dt, dsum, v);
    k_K<<<BB / RPB, 256, 0, stream>>>(users, pois, Dt, poi_emb, user_emb, dsum, Kh, K8);
    for (int it = 0; it < 10; it++) {
        k_it<<<IBLK, 1024, 0, stream>>>(K8, v, part, u);
        k_red<<<128, 256, 0, stream>>>(part, cap, v);
    }
    k_P<<<BB / RPP, 256, 0, stream>>>(Kh, u, v, out);
}